// Round 19
// baseline (620.026 us; speedup 1.0000x reference)
//
#include <hip/hip_runtime.h>
#include <math.h>

#define NPOINTS 16384
#define KNN     32
#define NBASIS  27

typedef unsigned long long ull;

// ===================== helpers =====================

__device__ __forceinline__ unsigned fkey(float f) {
  // monotone order-preserving map fp32 -> uint32 (3 VALU: ashr, or, xor)
  unsigned u = __float_as_uint(f);
  unsigned m = (unsigned)((int)u >> 31) | 0x80000000u;
  return u ^ m;
}

__device__ __forceinline__ ull shflx64(ull v, int mask) {
  int lo = __shfl_xor((int)(unsigned)(v & 0xFFFFFFFFULL), mask, 64);
  int hi = __shfl_xor((int)(unsigned)(v >> 32), mask, 64);
  return ((ull)(unsigned)hi << 32) | (ull)(unsigned)lo;
}

// count of set bits in m strictly below this lane (2 VALU)
__device__ __forceinline__ unsigned prefix64(ull m) {
  return __builtin_amdgcn_mbcnt_hi((unsigned)(m >> 32),
         __builtin_amdgcn_mbcnt_lo((unsigned)m, 0u));
}

// ===================== faithful ssyevd(3x3) port (double arith, fp32 eps) ============

__device__ __forceinline__ void slartg_dev(double f, double g, double* c, double* s, double* r) {
#pragma clang fp contract(off)
  // LAPACK >= 3.10 convention (c >= 0)
  if (g == 0.0) { *c = 1.0; *s = 0.0; *r = f; }
  else if (f == 0.0) { *c = 0.0; *s = (g >= 0.0 ? 1.0 : -1.0); *r = fabs(g); }
  else {
    double d = sqrt(f * f + g * g);
    *c = fabs(f) / d;
    *r = (f >= 0.0) ? d : -d;
    *s = g / (*r);
  }
}

__device__ __forceinline__ void slaev2_dev(double a, double b, double c,
                                           double* rt1, double* rt2, double* cs1, double* sn1) {
#pragma clang fp contract(off)
  double sm = a + c, df = a - c, adf = fabs(df), tb = b + b, ab = fabs(tb);
  double acmx, acmn;
  if (fabs(a) > fabs(c)) { acmx = a; acmn = c; } else { acmx = c; acmn = a; }
  double rt;
  if (adf > ab)      rt = adf * sqrt(1.0 + (ab / adf) * (ab / adf));
  else if (adf < ab) rt = ab * sqrt(1.0 + (adf / ab) * (adf / ab));
  else               rt = ab * sqrt(2.0);
  int sgn1;
  if (sm < 0.0) { *rt1 = 0.5 * (sm - rt); sgn1 = -1; *rt2 = (acmx / *rt1) * acmn - (b / *rt1) * b; }
  else if (sm > 0.0) { *rt1 = 0.5 * (sm + rt); sgn1 = 1; *rt2 = (acmx / *rt1) * acmn - (b / *rt1) * b; }
  else { *rt1 = 0.5 * rt; *rt2 = -0.5 * rt; sgn1 = 1; }
  int sgn2; double cs;
  if (df >= 0.0) { cs = df + rt; sgn2 = 1; } else { cs = df - rt; sgn2 = -1; }
  double acs = fabs(cs);
  if (acs > ab) { double ct = -tb / cs; double sn = 1.0 / sqrt(1.0 + ct * ct); *sn1 = sn; *cs1 = ct * sn; }
  else {
    if (ab == 0.0) { *cs1 = 1.0; *sn1 = 0.0; }
    else { double tn = -cs / tb; double c1 = 1.0 / sqrt(1.0 + tn * tn); *cs1 = c1; *sn1 = tn * c1; }
  }
  if (sgn1 == sgn2) { double tn = *cs1; *cs1 = -(*sn1); *sn1 = tn; }
}

// Input: lower triangle of symmetric 3x3 (fp32 cov). Output: V columns in DESCENDING
// eigenvalue order (LAPACK ascending, reversed) = np/jnp eigh + [:, :, ::-1].
__device__ void eigh3(float A00, float A10, float A20, float A11, float A21, float A22,
                      float V[3][3]) {
#pragma clang fp contract(off)
  const double EPS    = 5.9604644775390625e-08;   // fp32 slamch('E')
  const double EPS2   = EPS * EPS;
  const double SAFMIN = 1.1754943508222875e-38;   // fp32 slamch('S')
  double d[3], e[2];
  double tau = 0.0, v2 = 0.0;
  // ---- ssytd2 (uplo='L'), single Householder on [A10; A20]
  {
    double alpha = (double)A10, x = (double)A20;
    double a11 = (double)A11, a21 = (double)A21, a22 = (double)A22;
    double beta;
    if (x == 0.0) { tau = 0.0; v2 = 0.0; beta = alpha; }
    else {
      double nrm = sqrt(alpha * alpha + x * x);          // slapy2
      beta = (alpha >= 0.0) ? -nrm : nrm;                // -sign(nrm, alpha)
      tau = (beta - alpha) / beta;
      v2 = x / (alpha - beta);
    }
    if (tau != 0.0) {
      double w0 = tau * (a11 + a21 * v2);
      double w1 = tau * (a21 + a22 * v2);
      double cc = 0.5 * tau * (w0 + w1 * v2);
      w0 -= cc; w1 -= cc * v2;
      a11 -= 2.0 * w0;
      a21 -= (v2 * w0 + w1);
      a22 -= 2.0 * v2 * w1;
    }
    d[0] = (double)A00; d[1] = a11; d[2] = a22;
    e[0] = beta; e[1] = a21;
  }
  double Z[3][3] = { {1.0, 0.0, 0.0}, {0.0, 1.0, 0.0}, {0.0, 0.0, 1.0} };
  // ---- ssteqr('I', n=3)
  {
    int l1 = 1, jtot = 0;
    const int nmaxit = 90;
    double wc[2], wsn[2];
    while (l1 <= 3) {
      if (l1 > 1) e[l1 - 2] = 0.0;
      int m = 3;
      for (int mm = l1; mm <= 2; ++mm) {
        double tst = fabs(e[mm - 1]);
        if (tst == 0.0) { m = mm; break; }
        if (tst <= (sqrt(fabs(d[mm - 1])) * sqrt(fabs(d[mm]))) * EPS) { e[mm - 1] = 0.0; m = mm; break; }
      }
      int l = l1, lsv = l, lend = m, lendsv = lend;
      l1 = m + 1;
      if (lend == l) continue;
      double anorm = 0.0;
      for (int i = l; i <= lend; ++i)     anorm = fmax(anorm, fabs(d[i - 1]));
      for (int i = l; i <= lend - 1; ++i) anorm = fmax(anorm, fabs(e[i - 1]));
      if (anorm == 0.0) continue;
      if (fabs(d[lend - 1]) < fabs(d[l - 1])) { lend = lsv; l = lendsv; }
      if (lend > l) {
        // ===== QL =====
        bool done = false;
        while (!done) {
          int mq = lend;
          for (int mm = l; mm <= lend - 1; ++mm) {
            double tst = e[mm - 1] * e[mm - 1];
            if (tst <= (EPS2 * fabs(d[mm - 1])) * fabs(d[mm]) + SAFMIN) { mq = mm; break; }
          }
          if (mq < lend) e[mq - 1] = 0.0;
          double p = d[l - 1];
          if (mq == l) { d[l - 1] = p; ++l; if (l > lend) done = true; continue; }
          if (mq == l + 1) {
            double rt1, rt2, cc, ssn;
            slaev2_dev(d[l - 1], e[l - 1], d[l], &rt1, &rt2, &cc, &ssn);
            for (int i = 0; i < 3; ++i) {
              double t = Z[i][l];
              Z[i][l]     = cc * t - ssn * Z[i][l - 1];
              Z[i][l - 1] = ssn * t + cc * Z[i][l - 1];
            }
            d[l - 1] = rt1; d[l] = rt2; e[l - 1] = 0.0;
            l += 2; if (l > lend) done = true; continue;
          }
          if (jtot >= nmaxit) break;
          ++jtot;
          double g = (d[l] - p) / (2.0 * e[l - 1]);
          double r = sqrt(g * g + 1.0);
          g = d[mq - 1] - p + e[l - 1] / (g + ((g >= 0.0) ? r : -r));
          double ssn = 1.0, cc = 1.0;
          p = 0.0;
          for (int i = mq - 1; i >= l; --i) {
            double f = ssn * e[i - 1], b = cc * e[i - 1];
            slartg_dev(g, f, &cc, &ssn, &r);
            if (i != mq - 1) e[i] = r;
            g = d[i] - p;
            r = (d[i - 1] - g) * ssn + 2.0 * cc * b;
            p = ssn * r;
            d[i] = g + p;
            g = cc * r - b;
            wc[i - 1] = cc; wsn[i - 1] = -ssn;
          }
          for (int j = mq - 1; j >= l; --j) {
            double cj = wc[j - 1], sj = wsn[j - 1];
            for (int i = 0; i < 3; ++i) {
              double t = Z[i][j];
              Z[i][j]     = cj * t - sj * Z[i][j - 1];
              Z[i][j - 1] = sj * t + cj * Z[i][j - 1];
            }
          }
          d[l - 1] -= p; e[l - 1] = g;
        }
      } else {
        // ===== QR =====
        bool done = false;
        while (!done) {
          int mq = lend;
          for (int mm = l; mm >= lend + 1; --mm) {
            double tst = e[mm - 2] * e[mm - 2];
            if (tst <= (EPS2 * fabs(d[mm - 1])) * fabs(d[mm - 2]) + SAFMIN) { mq = mm; break; }
          }
          if (mq > lend) e[mq - 2] = 0.0;
          double p = d[l - 1];
          if (mq == l) { d[l - 1] = p; --l; if (l < lend) done = true; continue; }
          if (mq == l - 1) {
            double rt1, rt2, cc, ssn;
            slaev2_dev(d[l - 2], e[l - 2], d[l - 1], &rt1, &rt2, &cc, &ssn);
            for (int i = 0; i < 3; ++i) {
              double t = Z[i][l - 1];
              Z[i][l - 1] = cc * t - ssn * Z[i][l - 2];
              Z[i][l - 2] = ssn * t + cc * Z[i][l - 2];
            }
            d[l - 2] = rt1; d[l - 1] = rt2; e[l - 2] = 0.0;
            l -= 2; if (l < lend) done = true; continue;
          }
          if (jtot >= nmaxit) break;
          ++jtot;
          double g = (d[l - 2] - p) / (2.0 * e[l - 2]);
          double r = sqrt(g * g + 1.0);
          g = d[mq - 1] - p + e[l - 2] / (g + ((g >= 0.0) ? r : -r));
          double ssn = 1.0, cc = 1.0;
          p = 0.0;
          for (int i = mq; i <= l - 1; ++i) {
            double f = ssn * e[i - 1], b = cc * e[i - 1];
            slartg_dev(g, f, &cc, &ssn, &r);
            if (i != mq) e[i - 2] = r;
            g = d[i - 1] - p;
            r = (d[i] - g) * ssn + 2.0 * cc * b;
            p = ssn * r;
            d[i - 1] = g + p;
            g = cc * r - b;
            wc[i - 1] = cc; wsn[i - 1] = ssn;
          }
          for (int j = mq; j <= l - 1; ++j) {
            double cj = wc[j - 1], sj = wsn[j - 1];
            for (int i = 0; i < 3; ++i) {
              double t = Z[i][j];
              Z[i][j]     = cj * t - sj * Z[i][j - 1];
              Z[i][j - 1] = sj * t + cj * Z[i][j - 1];
            }
          }
          d[l - 1] -= p; e[l - 2] = g;
        }
      }
    }
    // ---- ascending selection sort with column swaps (as in ssteqr)
    for (int ii = 2; ii <= 3; ++ii) {
      int i0 = ii - 1, k = i0;
      double p = d[i0 - 1];
      for (int j = ii; j <= 3; ++j) if (d[j - 1] < p) { k = j; p = d[j - 1]; }
      if (k != i0) {
        d[k - 1] = d[i0 - 1]; d[i0 - 1] = p;
        for (int rr = 0; rr < 3; ++rr) { double t = Z[rr][i0 - 1]; Z[rr][i0 - 1] = Z[rr][k - 1]; Z[rr][k - 1] = t; }
      }
    }
  }
  // ---- sormtr: Z := H1 * Z
  if (tau != 0.0) {
    for (int j = 0; j < 3; ++j) {
      double w = Z[1][j] + v2 * Z[2][j];
      Z[1][j] -= tau * w;
      Z[2][j] -= tau * v2 * w;
    }
  }
  for (int i = 0; i < 3; ++i)
    for (int j = 0; j < 3; ++j)
      V[i][j] = (float)Z[i][2 - j];
}

// ===================== kernel 0: pack pos -> float4 {x,y,z,sq} =====================
__global__ __launch_bounds__(256) void pack_kernel(const float* __restrict__ pos,
                                                   float4* __restrict__ pos4) {
#pragma clang fp contract(off)
  int i = blockIdx.x * 256 + threadIdx.x;
  if (i < NPOINTS) {
    float x = pos[3 * i + 0], y = pos[3 * i + 1], z = pos[3 * i + 2];
    float sq = (x * x + y * y) + z * z;   // XLA reduce order (same as r6)
    pos4[i] = make_float4(x, y, z, sq);
  }
}

// ===================== kernel 1: exact KNN, double-buffered tiles (1 barrier/tile) ====
// Order: C = (fkey(d2) << 32) | (0xFFFFFFFF - idx). 32 smallest C == r6-verified
// semantics (key asc, ties -> HIGHER index first). Chain-A d2 unchanged.
// r19: 2x8KB tile double-buffer halves barrier count (2->1 per tile). Write of
// tile[cur^1] at iter t is safe: its last readers (iter t-1) are behind the
// end-of-iter barrier. Prefetch t+2 into NAMED regs (rule #20).
#define WPB  4    // waves per block
#define RPW  2    // rows per wave -> 8 rows per block
#define TPTS 512  // tile points (8 KB per buffer)
#define NTIL (NPOINTS / TPTS)
#define CAP  128  // candidate capacity per row (E[cnt]~44; serial fallback kept)

__global__ __launch_bounds__(256) void knn_kernel(const float4* __restrict__ pos4,
                                                  unsigned* __restrict__ idx_out) {
#pragma clang fp contract(off)
  __shared__ float4 tile[2][TPTS];         // 16 KB
  __shared__ ull cand[WPB][RPW][CAP];      // 8 KB
  __shared__ ull sel[WPB][RPW][KNN];       // 2 KB
  const int tid  = threadIdx.x;
  const int lane = tid & 63;
  const int wave = tid >> 6;
  const int rowbase = (blockIdx.x * WPB + wave) * RPW;
  const float INF = __int_as_float(0x7f800000);

  float rx[RPW], ry[RPW], rz[RPW], rq[RPW];
#pragma unroll
  for (int r = 0; r < RPW; ++r) {
    const float4 rp = pos4[rowbase + r];
    rx[r] = rp.x; ry[r] = rp.y; rz[r] = rp.z; rq[r] = rp.w;
  }

  // ---- phase A: per-lane MIN d2, dual chains; double-buffered tiles ----
  float kaA = INF, kbA = INF, kaB = INF, kbB = INF;   // [row0 even/odd, row1 even/odd]
  {
    // init: write tile[0], prefetch tile 1 into named regs
    float4 s0 = pos4[0 * 256 + tid];
    float4 s1 = pos4[1 * 256 + tid];
    tile[0][0 * 256 + tid] = s0;
    tile[0][1 * 256 + tid] = s1;
    s0 = pos4[TPTS + 0 * 256 + tid];
    s1 = pos4[TPTS + 1 * 256 + tid];
    __syncthreads();
    for (int t = 0; t < NTIL; ++t) {
      const int cur = t & 1;
      if (t + 1 < NTIL) {
        tile[cur ^ 1][0 * 256 + tid] = s0;
        tile[cur ^ 1][1 * 256 + tid] = s1;
      }
      if (t + 2 < NTIL) {
        const int base = (t + 2) * TPTS + tid;
        s0 = pos4[base + 0 * 256];
        s1 = pos4[base + 1 * 256];
      }
#pragma unroll 2
      for (int ch = 0; ch < TPTS / 64; ch += 2) {
        const float4 p0 = tile[cur][ch * 64 + lane];
        const float4 p1 = tile[cur][(ch + 1) * 64 + lane];
        {
          const float md0 = __builtin_fmaf(rz[0], p0.z, __builtin_fmaf(ry[0], p0.y, rx[0] * p0.x));
          kaA = fminf(kaA, (rq[0] + p0.w) - 2.0f * md0);
          const float md1 = __builtin_fmaf(rz[0], p1.z, __builtin_fmaf(ry[0], p1.y, rx[0] * p1.x));
          kbA = fminf(kbA, (rq[0] + p1.w) - 2.0f * md1);
          const float md2 = __builtin_fmaf(rz[1], p0.z, __builtin_fmaf(ry[1], p0.y, rx[1] * p0.x));
          kaB = fminf(kaB, (rq[1] + p0.w) - 2.0f * md2);
          const float md3 = __builtin_fmaf(rz[1], p1.z, __builtin_fmaf(ry[1], p1.y, rx[1] * p1.x));
          kbB = fminf(kbB, (rq[1] + p1.w) - 2.0f * md3);
        }
      }
      __syncthreads();
    }
  }

  // ---- per-row float threshold Tt = 32nd smallest of the 64 lane minima ----
  // Certified: <=31 global values strictly < T32, each in one lane => Tt >= T32.
  float Ttf[RPW];
#pragma unroll
  for (int r = 0; r < RPW; ++r) {
    float k1f = (r == 0) ? fminf(kaA, kbA) : fminf(kaB, kbB);   // exact lane-min
    int head = 0;
    float T = 0.f;
    for (int it = 0; it < KNN; ++it) {
      float v = (head == 0) ? k1f : INF;
      float m = v;
      for (int off = 1; off < 64; off <<= 1) {
        float o = __shfl_xor(m, off, 64);
        m = fminf(m, o);
      }
      ull win = __ballot(v == m);
      int wl = __ffsll((long long)win) - 1;
      if (lane == wl) ++head;
      T = m;
    }
    Ttf[r] = T;
  }
  __syncthreads();   // all waves done with tile buffers before phase B re-stages

  // ---- phase B: compact candidates with d2 <= Ttf (double-buffered + any-skip) ----
  unsigned cnt0 = 0, cnt1 = 0;
  const float T0 = Ttf[0], T1 = Ttf[1];
  {
    float4 s0 = pos4[0 * 256 + tid];
    float4 s1 = pos4[1 * 256 + tid];
    tile[0][0 * 256 + tid] = s0;
    tile[0][1 * 256 + tid] = s1;
    s0 = pos4[TPTS + 0 * 256 + tid];
    s1 = pos4[TPTS + 1 * 256 + tid];
    __syncthreads();
    for (int t = 0; t < NTIL; ++t) {
      const int cur = t & 1;
      if (t + 1 < NTIL) {
        tile[cur ^ 1][0 * 256 + tid] = s0;
        tile[cur ^ 1][1 * 256 + tid] = s1;
      }
      if (t + 2 < NTIL) {
        const int base = (t + 2) * TPTS + tid;
        s0 = pos4[base + 0 * 256];
        s1 = pos4[base + 1 * 256];
      }
#pragma unroll 2
      for (int ch = 0; ch < TPTS / 64; ++ch) {
        const int j = t * TPTS + ch * 64 + lane;
        const float4 p = tile[cur][ch * 64 + lane];
        const float md0 = __builtin_fmaf(rz[0], p.z, __builtin_fmaf(ry[0], p.y, rx[0] * p.x));
        const float d20 = (rq[0] + p.w) - 2.0f * md0;
        const float md1 = __builtin_fmaf(rz[1], p.z, __builtin_fmaf(ry[1], p.y, rx[1] * p.x));
        const float d21 = (rq[1] + p.w) - 2.0f * md1;
        const bool c0 = (d20 <= T0);
        const bool c1 = (d21 <= T1);
        if (__any(c0 || c1)) {             // exact skip: if false, both m==0, cnt+=0
          const ull m0 = __ballot(c0);
          if (c0) {
            unsigned slot = cnt0 + prefix64(m0);
            if (slot < CAP)
              cand[wave][0][slot] = ((ull)fkey(d20) << 32) | (ull)(0xFFFFFFFFu - (unsigned)j);
          }
          cnt0 += (unsigned)__popcll(m0);
          const ull m1 = __ballot(c1);
          if (c1) {
            unsigned slot = cnt1 + prefix64(m1);
            if (slot < CAP)
              cand[wave][1][slot] = ((ull)fkey(d21) << 32) | (ull)(0xFFFFFFFFu - (unsigned)j);
          }
          cnt1 += (unsigned)__popcll(m1);
        }
      }
      __syncthreads();
    }
  }
  __builtin_amdgcn_s_waitcnt(0);   // drain our ds_writes (wave-private region)

  unsigned cnt[RPW];
  cnt[0] = cnt0; cnt[1] = cnt1;
#pragma unroll
  for (int r = 0; r < RPW; ++r) {
    if (cnt[r] <= (unsigned)CAP) {
      // exact wave-parallel extraction of 32 smallest C from <=128 candidates
      ull c0v = (lane < (int)cnt[r]) ? cand[wave][r][lane] : ~0ULL;
      ull c1v = ((lane + 64) < (int)cnt[r]) ? cand[wave][r][lane + 64] : ~0ULL;
      ull lo = (c0v < c1v) ? c0v : c1v;
      ull hi = (c0v < c1v) ? c1v : c0v;
      int head = 0;
      for (int it = 0; it < KNN; ++it) {
        ull v = (head == 0) ? lo : ((head == 1) ? hi : ~0ULL);
        ull m = v;
        for (int off = 1; off < 64; off <<= 1) {
          ull o = shflx64(m, off);
          m = (o < m) ? o : m;
        }
        ull win = __ballot(v == m);
        int wl = __ffsll((long long)win) - 1;
        if (lane == wl) ++head;
        if (lane == 0) sel[wave][r][it] = m;
      }
    } else {
      // exact serial fallback (probability ~0)
      if (lane == 0) {
        int n2 = 0;
        for (int j = 0; j < NPOINTS; ++j) {
          const float4 p = pos4[j];
          const float mdot = __builtin_fmaf(rz[r], p.z, __builtin_fmaf(ry[r], p.y, rx[r] * p.x));
          const float d2 = (rq[r] + p.w) - 2.0f * mdot;
          const unsigned key = fkey(d2);
          const ull C = ((ull)key << 32) | (ull)(0xFFFFFFFFu - (unsigned)j);
          if (n2 < KNN) {
            int b = n2 - 1;
            while (b >= 0 && sel[wave][r][b] > C) { sel[wave][r][b + 1] = sel[wave][r][b]; --b; }
            sel[wave][r][b + 1] = C;
            ++n2;
          } else if (C < sel[wave][r][KNN - 1]) {
            int b = KNN - 2;
            while (b >= 0 && sel[wave][r][b] > C) { sel[wave][r][b + 1] = sel[wave][r][b]; --b; }
            sel[wave][r][b + 1] = C;
          }
        }
      }
    }
  }
  __builtin_amdgcn_s_waitcnt(0);

  // finalize (lane 0): C-ascending == (key asc, idx desc). Emission wants
  // (key asc, idx asc): reverse idx within bit-equal-key runs only (rare).
  if (lane == 0) {
#pragma unroll
    for (int r = 0; r < RPW; ++r) {
      unsigned kk[KNN], ii[KNN];
      for (int a = 0; a < KNN; ++a) {
        ull C = sel[wave][r][a];
        kk[a] = (unsigned)(C >> 32);
        ii[a] = 0xFFFFFFFFu - (unsigned)(C & 0xFFFFFFFFULL);
      }
      int a = 0;
      while (a < KNN) {
        int b = a;
        while (b + 1 < KNN && kk[b + 1] == kk[a]) ++b;
        for (int x = a, y = b; x < y; ++x, --y) { unsigned tmp = ii[x]; ii[x] = ii[y]; ii[y] = tmp; }
        a = b + 1;
      }
      unsigned ob = (unsigned)(rowbase + r) * KNN;
      for (int q = 0; q < KNN; ++q) idx_out[ob + q] = ii[q];
    }
  }
}

// ===================== kernel 2: mean + cov + eigh per point (fp32) =====================
// 64-thread blocks x 256 blocks -> all 256 CUs busy.
__global__ __launch_bounds__(64) void pca_kernel(const float4* __restrict__ pos4,
                                                 const unsigned* __restrict__ idx,
                                                 float* __restrict__ center,
                                                 float* __restrict__ Vmat) {
#pragma clang fp contract(off)
  int n = blockIdx.x * 64 + threadIdx.x;
  if (n >= NPOINTS) return;
  float sx = 0.f, sy = 0.f, sz = 0.f;
  for (int k = 0; k < KNN; ++k) {
    unsigned j = idx[n * KNN + k];
    const float4 p = pos4[j];
    sx += p.x; sy += p.y; sz += p.z;
  }
  float cx = sx * 0.03125f, cy = sy * 0.03125f, cz = sz * 0.03125f;
  float c00 = 0.f, c10 = 0.f, c20 = 0.f, c11 = 0.f, c21 = 0.f, c22 = 0.f;
  for (int k = 0; k < KNN; ++k) {
    unsigned j = idx[n * KNN + k];
    const float4 p = pos4[j];
    float lx = p.x - cx;
    float ly = p.y - cy;
    float lz = p.z - cz;
    c00 += lx * lx; c10 += lx * ly; c20 += lx * lz;
    c11 += ly * ly; c21 += ly * lz; c22 += lz * lz;
  }
  c00 *= 0.03125f; c10 *= 0.03125f; c20 *= 0.03125f;
  c11 *= 0.03125f; c21 *= 0.03125f; c22 *= 0.03125f;
  float V[3][3];
  eigh3(c00, c10, c20, c11, c21, c22, V);
  center[n * 3 + 0] = cx; center[n * 3 + 1] = cy; center[n * 3 + 2] = cz;
  for (int i = 0; i < 3; ++i)
    for (int j2 = 0; j2 < 3; ++j2)
      Vmat[n * 9 + i * 3 + j2] = V[i][j2];
}

// ===================== kernel 3: basis + G[b,i] + i-split matmul ====================
// matmul i-SPLIT across waves: wave w covers i in [16w,16w+16) for ALL 4 points,
// loading each coeff value ONCE (1.8GB L2 coeff traffic). Partials reduced in
// fixed order (w0+w1)+(w2+w3) — smooth fp change only.
#define NT 4
__global__ __launch_bounds__(256) void conv_kernel(const float4* __restrict__ pos4,
                                                   const float* __restrict__ chan,
                                                   const float* __restrict__ coeff,
                                                   const unsigned* __restrict__ idx,
                                                   const float* __restrict__ center,
                                                   const float* __restrict__ Vmat,
                                                   float* __restrict__ out) {
#pragma clang fp contract(off)
  __shared__ float G[NT][NBASIS][64];      // 27 KB
  __shared__ float P[NT][NT][64];          // partials [wave][point][lane], 4 KB
  __shared__ float Tsh[NT][64];            // 1 KB
  const int tid  = threadIdx.x;
  const int lane = tid & 63;
  const int wave = tid >> 6;
  const int n0 = blockIdx.x * NT;
  const int n  = n0 + wave;

  {
    const float cx = center[n * 3 + 0], cy = center[n * 3 + 1], cz = center[n * 3 + 2];
    const float V00 = Vmat[n * 9 + 0], V01 = Vmat[n * 9 + 1], V02 = Vmat[n * 9 + 2];
    const float V10 = Vmat[n * 9 + 3], V11 = Vmat[n * 9 + 4], V12 = Vmat[n * 9 + 5];
    const float V20 = Vmat[n * 9 + 6], V21 = Vmat[n * 9 + 7], V22 = Vmat[n * 9 + 8];
    float g[NBASIS];
#pragma unroll
    for (int b = 0; b < NBASIS; ++b) g[b] = 0.f;
    for (int k = 0; k < KNN; ++k) {
      const unsigned j = idx[n * KNN + k];
      const float4 pj = pos4[j];                    // wave-uniform -> scalar load
      const float lx = pj.x - cx;
      const float ly = pj.y - cy;
      const float lz = pj.z - cz;
      const float X  = lx * V00 + ly * V10 + lz * V20;
      const float Y  = lx * V01 + ly * V11 + lz * V21;
      const float Zc = lx * V02 + ly * V12 + lz * V22;
      const float r = sqrtf(((X * X + Y * Y) + Zc * Zc) + 1e-8f);
      float u = Zc / r;
      u = fminf(fmaxf(u, -0.999999f), 0.999999f);
      const float ct1 = u, ct2 = 2.f * u * u - 1.f;
      const float rho2 = X * X + Y * Y;
      const float cp1 = (rho2 > 0.f) ? (X / sqrtf(rho2)) : 1.f;
      const float cp2 = 2.f * cp1 * cp1 - 1.f;
      const float f = chan[(size_t)j * 64 + lane];
      const float pr1 = r, pr2 = r * r;
      float tc[9];
      tc[0] = 1.f; tc[1] = cp1; tc[2] = cp2;
      tc[3] = ct1; tc[4] = ct1 * cp1; tc[5] = ct1 * cp2;
      tc[6] = ct2; tc[7] = ct2 * cp1; tc[8] = ct2 * cp2;
#pragma unroll
      for (int m9 = 0; m9 < 9; ++m9) {
        g[m9]      = __builtin_fmaf(tc[m9],       f, g[m9]);
        g[9 + m9]  = __builtin_fmaf(pr1 * tc[m9], f, g[9 + m9]);
        g[18 + m9] = __builtin_fmaf(pr2 * tc[m9], f, g[18 + m9]);
      }
    }
#pragma unroll
    for (int b = 0; b < NBASIS; ++b) G[wave][b][lane] = g[b];
  }
  __syncthreads();

  // i-split matmul: this wave covers i in [wave*16, wave*16+16) for all 4 points.
  float a0 = 0.f, a1 = 0.f, a2 = 0.f, a3 = 0.f;   // named accumulators (rule #20)
  for (int b = 0; b < NBASIS; ++b) {
    const float4* g0p = (const float4*)(&G[0][b][wave * 16]);
    const float4* g1p = (const float4*)(&G[1][b][wave * 16]);
    const float4* g2p = (const float4*)(&G[2][b][wave * 16]);
    const float4* g3p = (const float4*)(&G[3][b][wave * 16]);
    const float* cp = coeff + (size_t)(b * 64 + wave * 16) * 64 + lane;
#pragma unroll
    for (int i4 = 0; i4 < 4; ++i4) {
      const float c0 = cp[(i4 * 4 + 0) * 64];
      const float c1 = cp[(i4 * 4 + 1) * 64];
      const float c2 = cp[(i4 * 4 + 2) * 64];
      const float c3 = cp[(i4 * 4 + 3) * 64];
      const float4 q0 = g0p[i4];
      const float4 q1 = g1p[i4];
      const float4 q2 = g2p[i4];
      const float4 q3 = g3p[i4];
      a0 = __builtin_fmaf(c0, q0.x, a0); a0 = __builtin_fmaf(c1, q0.y, a0);
      a0 = __builtin_fmaf(c2, q0.z, a0); a0 = __builtin_fmaf(c3, q0.w, a0);
      a1 = __builtin_fmaf(c0, q1.x, a1); a1 = __builtin_fmaf(c1, q1.y, a1);
      a1 = __builtin_fmaf(c2, q1.z, a1); a1 = __builtin_fmaf(c3, q1.w, a1);
      a2 = __builtin_fmaf(c0, q2.x, a2); a2 = __builtin_fmaf(c1, q2.y, a2);
      a2 = __builtin_fmaf(c2, q2.z, a2); a2 = __builtin_fmaf(c3, q2.w, a2);
      a3 = __builtin_fmaf(c0, q3.x, a3); a3 = __builtin_fmaf(c1, q3.y, a3);
      a3 = __builtin_fmaf(c2, q3.z, a3); a3 = __builtin_fmaf(c3, q3.w, a3);
    }
  }
  P[wave][0][lane] = a0;
  P[wave][1][lane] = a1;
  P[wave][2][lane] = a2;
  P[wave][3][lane] = a3;
  __syncthreads();

  // reduce: wave w finalizes point w with fixed order (w0+w1)+(w2+w3)
  {
    const float s = ((P[0][wave][lane] + P[1][wave][lane]) +
                     (P[2][wave][lane] + P[3][wave][lane])) * 0.03125f;
    Tsh[wave][lane] = s;
  }
  __syncthreads();
  {
    const int o = tid >> 2, nn = tid & 3;             // 256 threads = 4 pts x 64 outs
    out[(size_t)o * NPOINTS + (n0 + nn)] = Tsh[nn][o];
  }
}

// ===================== launch =====================
extern "C" void kernel_launch(void* const* d_in, const int* in_sizes, int n_in,
                              void* d_out, int out_size, void* d_ws, size_t ws_size,
                              hipStream_t stream) {
  (void)in_sizes; (void)n_in; (void)out_size; (void)ws_size;
  const float* pos   = (const float*)d_in[0];
  const float* chan  = (const float*)d_in[1];
  const float* coeff = (const float*)d_in[2];
  float* out = (float*)d_out;
  unsigned char* ws = (unsigned char*)d_ws;
  float4*   pos4   = (float4*)(ws);                                    // 256 KiB
  unsigned* idx    = (unsigned*)(ws + (size_t)NPOINTS * 16);           // 2 MiB
  float*    center = (float*)(ws + (size_t)NPOINTS * 16 + (size_t)NPOINTS * KNN * 4);          // 192 KiB
  float*    Vmat   = (float*)(ws + (size_t)NPOINTS * 16 + (size_t)NPOINTS * KNN * 4
                              + (size_t)NPOINTS * 12);                 // 576 KiB
  hipLaunchKernelGGL(pack_kernel, dim3(NPOINTS / 256),         dim3(256), 0, stream, pos, pos4);
  hipLaunchKernelGGL(knn_kernel,  dim3(NPOINTS / (WPB * RPW)), dim3(256), 0, stream, pos4, idx);
  hipLaunchKernelGGL(pca_kernel,  dim3(NPOINTS / 64),          dim3(64),  0, stream, pos4, idx, center, Vmat);
  hipLaunchKernelGGL(conv_kernel, dim3(NPOINTS / NT),          dim3(256), 0, stream, pos4, chan, coeff, idx, center, Vmat, out);
}